// Round 7
// baseline (243.622 us; speedup 1.0000x reference)
//
#include <hip/hip_runtime.h>
#include <hip/hip_bf16.h>

// Problem constants (set_attention): B=4, Nq=Nk=2048, D_IN=512, H=8, HS=64
#define BB   4
#define NQ   2048
#define NKK  2048
#define DIN  512
#define NH   8
#define HS   64
#define HD   512  // NH*HS

typedef __hip_bfloat16 bf16;
typedef unsigned short ushort_t;
typedef __attribute__((ext_vector_type(8))) short short8;  // 8 bf16 (4 VGPRs)
typedef __attribute__((ext_vector_type(4))) float f32x4;   // MFMA C/D

__device__ __forceinline__ unsigned short f2bu(float x) {
  bf16 h = __float2bfloat16(x);
  return *(unsigned short*)&h;
}

// ---------------------------------------------------------------------------
// Kernel 0a: f32 -> bf16 convert of the two activations (q, k).
// grid (4096, 2); 256 thr; 4 elems/thread.
// ---------------------------------------------------------------------------
__global__ __launch_bounds__(256) void cvt_kernel(
    const float* __restrict__ q, const float* __restrict__ k,
    ushort_t* __restrict__ Xb) {
  const float* src = blockIdx.y ? k : q;
  ushort_t* dst = Xb + (size_t)blockIdx.y * 8192 * 512;
  size_t i = ((size_t)blockIdx.x * 256 + threadIdx.x) * 4;
  float4 v = *(const float4*)(src + i);
  __align__(8) ushort_t t4[4] = {f2bu(v.x), f2bu(v.y), f2bu(v.z), f2bu(v.w)};
  *(uint2*)(dst + i) = *(uint2*)t4;
}

// ---------------------------------------------------------------------------
// Kernel 0b: weight transpose + bf16 convert.
// z<3:  W[512k][512n] f32 -> Wt_z[n][k] bf16   (64x64 tiles via LDS)
// z==3: Wh[512k][64n] f32 -> Wht[n][k] bf16
// ---------------------------------------------------------------------------
__global__ __launch_bounds__(256) void wtrans_kernel(
    const float* __restrict__ Wq, const float* __restrict__ Wk,
    const float* __restrict__ Wv, const float* __restrict__ Wh,
    ushort_t* __restrict__ Wt, ushort_t* __restrict__ Wht) {
  const int z = blockIdx.z;
  const float* src;
  ushort_t* dst;
  int S;
  if (z < 3) {
    src = (z == 0) ? Wq : (z == 1) ? Wk : Wv;
    dst = Wt + (size_t)z * 512 * 512;
    S = 512;
  } else {
    if (blockIdx.y != 0) return;
    src = Wh;
    dst = Wht;
    S = 64;
  }
  const int k0 = blockIdx.x * 64;
  const int n0 = (z < 3) ? blockIdx.y * 64 : 0;

  __shared__ ushort_t Ls[64 * 72];
  const int tid = threadIdx.x;
  {
    int r = tid >> 2, cb = (tid & 3) * 16;
    const float* sp = src + (size_t)(k0 + r) * S + n0 + cb;
#pragma unroll
    for (int ii = 0; ii < 4; ++ii) {
      float4 f = *(const float4*)(sp + ii * 4);
      __align__(8) ushort_t t4[4] = {f2bu(f.x), f2bu(f.y), f2bu(f.z), f2bu(f.w)};
      *(uint2*)(&Ls[r * 72 + cb + ii * 4]) = *(uint2*)t4;
    }
  }
  __syncthreads();
  {
    int rr = tid >> 2, tb = (tid & 3) * 16;
    __align__(16) ushort_t tmp[16];
#pragma unroll
    for (int j = 0; j < 16; ++j) tmp[j] = Ls[(tb + j) * 72 + rr];
    ushort_t* dp = dst + (size_t)(n0 + rr) * 512 + k0 + tb;
    *(int4*)dp       = ((int4*)tmp)[0];
    *(int4*)(dp + 8) = ((int4*)tmp)[1];
  }
}

// ---------------------------------------------------------------------------
// Kernel 1: QKV projections, bf16 MFMA, double-buffered. Y = Xb @ Wt^T.
// Both operands already bf16 (Xb from cvt, Wt pre-transposed [n][k]):
// staging is pure int4 copies. 128x128 tile, BK=32, 4 waves x 64x64 out.
// ---------------------------------------------------------------------------
__global__ __launch_bounds__(256) void proj_kernel(
    const ushort_t* __restrict__ Xb, const ushort_t* __restrict__ Wt,
    ushort_t* __restrict__ Qf, ushort_t* __restrict__ Kf,
    ushort_t* __restrict__ Vf) {
  const int z = blockIdx.z;
  const ushort_t* Xz = Xb + (size_t)(z ? 1 : 0) * 8192 * 512;
  const ushort_t* Wz = Wt + (size_t)z * 512 * 512;
  ushort_t* Y = (z == 0) ? Qf : (z == 1) ? Kf : Vf;
  const float sc = (z == 0) ? 0.125f : 1.0f;  // fold 1/sqrt(64) into Q

  __shared__ ushort_t As[2 * 128 * 40];  // [buf][m][k]
  __shared__ ushort_t Bs[2 * 128 * 40];  // [buf][n][k]

  const int tid  = threadIdx.x;
  const int lane = tid & 63;
  const int w    = tid >> 6;
  const int quad = lane >> 4;
  const int c    = lane & 15;
  const int wm   = w >> 1, wn = w & 1;

  const int m0 = blockIdx.y * 128;
  const int n0 = blockIdx.x * 128;
  const int sm  = tid >> 1;
  const int skb = (tid & 1) * 16;

  int4 xa[2], wb[2];
  auto load_t = [&](int k0) {
    const ushort_t* xp = Xz + (size_t)(m0 + sm) * DIN + k0 + skb;
    xa[0] = *(const int4*)xp;
    xa[1] = *(const int4*)(xp + 8);
    const ushort_t* wp = Wz + (size_t)(n0 + sm) * 512 + k0 + skb;
    wb[0] = *(const int4*)wp;
    wb[1] = *(const int4*)(wp + 8);
  };
  auto store_t = [&](int buf) {
    *(int4*)(&As[buf * 5120 + sm * 40 + skb])     = xa[0];
    *(int4*)(&As[buf * 5120 + sm * 40 + skb + 8]) = xa[1];
    *(int4*)(&Bs[buf * 5120 + sm * 40 + skb])     = wb[0];
    *(int4*)(&Bs[buf * 5120 + sm * 40 + skb + 8]) = wb[1];
  };

  f32x4 acc[4][4];
#pragma unroll
  for (int m = 0; m < 4; ++m)
#pragma unroll
    for (int n = 0; n < 4; ++n) acc[m][n] = (f32x4)0.0f;

  load_t(0);
  store_t(0);
  __syncthreads();

  for (int t = 0; t < 16; ++t) {
    const int cur = t & 1;
    if (t < 15) load_t((t + 1) * 32);
    const ushort_t* as = As + cur * 5120;
    const ushort_t* bs = Bs + cur * 5120;
    short8 af[4], bfr[4];
#pragma unroll
    for (int m = 0; m < 4; ++m)
      af[m] = *(const short8*)(&as[(wm * 64 + m * 16 + c) * 40 + quad * 8]);
#pragma unroll
    for (int n = 0; n < 4; ++n)
      bfr[n] = *(const short8*)(&bs[(wn * 64 + n * 16 + c) * 40 + quad * 8]);
#pragma unroll
    for (int m = 0; m < 4; ++m)
#pragma unroll
      for (int n = 0; n < 4; ++n)
        acc[m][n] = __builtin_amdgcn_mfma_f32_16x16x32_bf16(af[m], bfr[n], acc[m][n], 0, 0, 0);
    if (t < 15) store_t(cur ^ 1);
    __syncthreads();
  }

#pragma unroll
  for (int m = 0; m < 4; ++m)
#pragma unroll
    for (int n = 0; n < 4; ++n)
#pragma unroll
      for (int r = 0; r < 4; ++r) {
        int row = m0 + wm * 64 + m * 16 + quad * 4 + r;
        int col = n0 + wn * 64 + n * 16 + c;
        Y[(size_t)row * HD + col] = f2bu(acc[m][n][r] * sc);
      }
}

// ---------------------------------------------------------------------------
// Kernel 1b: V transpose. Vf[(b*2048+t)*512 + cc] -> Vt[(b*512+cc)*2048 + t].
// ---------------------------------------------------------------------------
__global__ __launch_bounds__(256) void vtrans_kernel(
    const ushort_t* __restrict__ Vf, ushort_t* __restrict__ Vt) {
  const int b  = blockIdx.z;
  const int t0 = blockIdx.x * 64;
  const int c0 = blockIdx.y * 64;
  __shared__ ushort_t Ls[64 * 72];
  const int tid = threadIdx.x;
  {
    int r = tid >> 2, cb = (tid & 3) * 16;
    const ushort_t* src = Vf + (size_t)(b * NQ + t0 + r) * HD + c0 + cb;
    *(int4*)(&Ls[r * 72 + cb])     = *(const int4*)src;
    *(int4*)(&Ls[r * 72 + cb + 8]) = *(const int4*)(src + 8);
  }
  __syncthreads();
  {
    int rr = tid >> 2, tb = (tid & 3) * 16;
    __align__(16) ushort_t tmp[16];
#pragma unroll
    for (int j = 0; j < 16; ++j) tmp[j] = Ls[(tb + j) * 72 + rr];
    ushort_t* dst = Vt + (size_t)(b * HD + c0 + rr) * NKK + t0 + tb;
    *(int4*)dst       = ((int4*)tmp)[0];
    *(int4*)(dst + 8) = ((int4*)tmp)[1];
  }
}

// ---------------------------------------------------------------------------
// Kernel 2: MFMA flash attention, key-split x2 for occupancy.
// Block = (qb, h, b*2+ks): 128 q rows, keys [ks*1024, ks*1024+1024).
// Single-buffer LDS (36.9KB -> 4 blocks/CU) + register prefetch, 2 barriers
// per tile. Writes unnormalized O (f32) + row-sums L; reduce kernel merges.
// ---------------------------------------------------------------------------
__global__ __launch_bounds__(256, 4) void attn_kernel(
    const ushort_t* __restrict__ Qf, const ushort_t* __restrict__ Kf,
    const ushort_t* __restrict__ Vt, float* __restrict__ Op,
    float* __restrict__ Lsum) {
  const int qb = blockIdx.x;
  const int h  = blockIdx.y;
  const int b  = blockIdx.z >> 1;
  const int ks = blockIdx.z & 1;

  __shared__ ushort_t Kt[64 * 72];      // [key][d]
  __shared__ ushort_t Vs[64 * 72];      // [d][key]
  __shared__ ushort_t Ps[4 * 32 * 72];  // per-wave [q_local][key]

  const int tid  = threadIdx.x;
  const int lane = tid & 63;
  const int w    = tid >> 6;
  const int quad = lane >> 4;
  const int c    = lane & 15;

  const int q0 = qb * 128 + w * 32;
  const int kbase = ks * 1024;

  // Q as the B operand (regs all kernel)
  short8 bq[2][2];
#pragma unroll
  for (int nq = 0; nq < 2; ++nq)
#pragma unroll
    for (int kk = 0; kk < 2; ++kk)
      bq[nq][kk] = *(const short8*)(Qf + (size_t)(b * NQ + q0 + nq * 16 + c) * HD +
                                    h * HS + kk * 32 + quad * 8);

  f32x4 o[2][4];
#pragma unroll
  for (int m = 0; m < 2; ++m)
#pragma unroll
    for (int n = 0; n < 4; ++n) o[m][n] = (f32x4)0.0f;
  float lsum[2] = {0.0f, 0.0f};

  ushort_t* psw = Ps + w * 32 * 72;

  int4 pk[2], pv[2];
  auto load_t = [&](int kt) {  // kt: local tile 0..15
#pragma unroll
    for (int i = 0; i < 2; ++i) {
      int g = i * 256 + tid, row = g >> 3, gr = g & 7;
      pk[i] = *(const int4*)(Kf + (size_t)(b * NKK + kbase + kt * 64 + row) * HD +
                             h * HS + gr * 8);
      pv[i] = *(const int4*)(Vt + (size_t)((b * NH + h) * HS + row) * NKK +
                             kbase + kt * 64 + gr * 8);
    }
  };
  auto store_t = [&]() {
#pragma unroll
    for (int i = 0; i < 2; ++i) {
      int g = i * 256 + tid, row = g >> 3, gr = g & 7;
      *(int4*)(Kt + row * 72 + gr * 8) = pk[i];
      *(int4*)(Vs + row * 72 + gr * 8) = pv[i];
    }
  };

  load_t(0);
  store_t();
  __syncthreads();

  for (int kt = 0; kt < 16; ++kt) {
    if (kt < 15) load_t(kt + 1);  // global->regs, in flight during compute

    // S^T = K @ Q^T
    f32x4 s[4][2];
#pragma unroll
    for (int mk = 0; mk < 4; ++mk)
#pragma unroll
      for (int nq = 0; nq < 2; ++nq) s[mk][nq] = (f32x4)0.0f;
#pragma unroll
    for (int mk = 0; mk < 4; ++mk)
#pragma unroll
      for (int kk = 0; kk < 2; ++kk) {
        short8 ak = *(const short8*)(Kt + (mk * 16 + c) * 72 + kk * 32 + quad * 8);
#pragma unroll
        for (int nq = 0; nq < 2; ++nq)
          s[mk][nq] = __builtin_amdgcn_mfma_f32_16x16x32_bf16(ak, bq[nq][kk], s[mk][nq], 0, 0, 0);
      }

    // P = exp(S^T); packed 8B writes to wave-private Ps[q][key]
#pragma unroll
    for (int mk = 0; mk < 4; ++mk)
#pragma unroll
      for (int nq = 0; nq < 2; ++nq) {
        float p0 = __expf(s[mk][nq][0]);
        float p1 = __expf(s[mk][nq][1]);
        float p2 = __expf(s[mk][nq][2]);
        float p3 = __expf(s[mk][nq][3]);
        lsum[nq] += (p0 + p1) + (p2 + p3);
        unsigned int lo = (unsigned int)f2bu(p0) | ((unsigned int)f2bu(p1) << 16);
        unsigned int hi = (unsigned int)f2bu(p2) | ((unsigned int)f2bu(p3) << 16);
        *(uint2*)(psw + (nq * 16 + c) * 72 + mk * 16 + quad * 4) = make_uint2(lo, hi);
      }

    // O += P @ V
    short8 ap[2][2];
#pragma unroll
    for (int mq = 0; mq < 2; ++mq)
#pragma unroll
      for (int kk = 0; kk < 2; ++kk)
        ap[mq][kk] = *(const short8*)(psw + (mq * 16 + c) * 72 + kk * 32 + quad * 8);
#pragma unroll
    for (int nd = 0; nd < 4; ++nd)
#pragma unroll
      for (int kk = 0; kk < 2; ++kk) {
        short8 bv = *(const short8*)(Vs + (nd * 16 + c) * 72 + kk * 32 + quad * 8);
#pragma unroll
        for (int mq = 0; mq < 2; ++mq)
          o[mq][nd] = __builtin_amdgcn_mfma_f32_16x16x32_bf16(ap[mq][kk], bv, o[mq][nd], 0, 0, 0);
      }

    if (kt < 15) {
      __syncthreads();  // all waves done reading K/V LDS
      store_t();        // waits vmcnt, refills single buffer
      __syncthreads();
    }
  }

  // column sums (over this key half); all quads end with the total for col c
  const size_t rowbase = ((size_t)ks * BB * NH + b * NH + h) * NQ;
#pragma unroll
  for (int nq = 0; nq < 2; ++nq) {
    float v = lsum[nq];
    v += __shfl_xor(v, 16);
    v += __shfl_xor(v, 32);
    if (quad == 0) Lsum[rowbase + q0 + nq * 16 + c] = v;
  }

  // unnormalized O partial: Op[(ks,b,h,q)][d] f32
#pragma unroll
  for (int mq = 0; mq < 2; ++mq)
#pragma unroll
    for (int nd = 0; nd < 4; ++nd)
#pragma unroll
      for (int r = 0; r < 4; ++r) {
        size_t idx = (rowbase + q0 + mq * 16 + quad * 4 + r) * 64 + nd * 16 + c;
        Op[idx] = o[mq][nd][r];
      }
}

// ---------------------------------------------------------------------------
// Kernel 2b: merge the two key-halves: CTX = (O0+O1)/(L0+L1), bf16.
// ---------------------------------------------------------------------------
__global__ __launch_bounds__(256) void reduce_kernel(
    const float* __restrict__ Op, const float* __restrict__ Lsum,
    ushort_t* __restrict__ CTX) {
  const size_t HALF = (size_t)BB * NH * NQ * 64;  // 4,194,304
  size_t gid = (size_t)blockIdx.x * 256 + threadIdx.x;
  int row = (int)(gid >> 6);
  int d   = (int)(gid & 63);
  float l = Lsum[row] + Lsum[BB * NH * NQ + row];
  float v = Op[gid] + Op[HALF + gid];
  int b = row >> 14, h = (row >> 11) & 7, q = row & 2047;
  CTX[((size_t)(b * NQ + q)) * HD + h * HS + d] = f2bu(v / l);
}

// ---------------------------------------------------------------------------
// Kernel 3: out[8192,64] = CTX[8192,512] @ Wh[512,64], LDS-free MFMA.
// ---------------------------------------------------------------------------
__global__ __launch_bounds__(64) void outproj_kernel(
    const ushort_t* __restrict__ CTX, const ushort_t* __restrict__ Wht,
    float* __restrict__ out) {
  const int lane = threadIdx.x & 63;
  const int quad = lane >> 4, c = lane & 15;
  const int m0 = blockIdx.x * 16;

  f32x4 o[4];
#pragma unroll
  for (int n = 0; n < 4; ++n) o[n] = (f32x4)0.0f;

  const ushort_t* arow = CTX + (size_t)(m0 + c) * HD;
#pragma unroll 4
  for (int ks = 0; ks < 16; ++ks) {
    short8 a = *(const short8*)(arow + ks * 32 + quad * 8);
#pragma unroll
    for (int nd = 0; nd < 4; ++nd) {
      short8 bn = *(const short8*)(Wht + (size_t)(nd * 16 + c) * 512 + ks * 32 + quad * 8);
      o[nd] = __builtin_amdgcn_mfma_f32_16x16x32_bf16(a, bn, o[nd], 0, 0, 0);
    }
  }
#pragma unroll
  for (int nd = 0; nd < 4; ++nd)
#pragma unroll
    for (int r = 0; r < 4; ++r)
      out[(size_t)(m0 + quad * 4 + r) * HS + nd * 16 + c] = o[nd][r];
}

// ---------------------------------------------------------------------------
extern "C" void kernel_launch(void* const* d_in, const int* in_sizes, int n_in,
                              void* d_out, int out_size, void* d_ws,
                              size_t ws_size, hipStream_t stream) {
  const float* q  = (const float*)d_in[0];
  const float* k  = (const float*)d_in[1];
  const float* Wq = (const float*)d_in[2];
  const float* Wk = (const float*)d_in[3];
  const float* Wv = (const float*)d_in[4];
  const float* Wh = (const float*)d_in[5];
  float* out = (float*)d_out;

  // Workspace layout (bytes). E2 = one bf16 [8192x512] tensor = 8 MiB.
  // Op (32 MiB f32) aliases Vf+Xb (both dead before attn runs).
  const size_t E  = (size_t)BB * NQ * HD;  // 4,194,304 elems
  const size_t E2 = E * 2;                 // bytes per bf16 tensor
  char* base = (char*)d_ws;
  ushort_t* Qf  = (ushort_t*)(base);
  ushort_t* Kf  = (ushort_t*)(base + E2);
  ushort_t* Vt  = (ushort_t*)(base + 2 * E2);
  ushort_t* CTX = (ushort_t*)(base + 3 * E2);
  ushort_t* Wt  = (ushort_t*)(base + 4 * E2);                 // 1.5 MiB
  ushort_t* Wht = (ushort_t*)(base + 4 * E2 + 1572864);       // 64 KiB
  float*    Ls  = (float*)   (base + 4 * E2 + 1638400);       // 512 KiB
  char* dyn = base + 4 * E2 + 1638400 + 524288;
  ushort_t* Vf  = (ushort_t*)(dyn);                           // 8 MiB
  ushort_t* Xb  = (ushort_t*)(dyn + E2);                      // 16 MiB
  float*    Op  = (float*)   (dyn);                           // 32 MiB (alias)

  cvt_kernel<<<dim3(4096, 2), 256, 0, stream>>>(q, k, Xb);
  wtrans_kernel<<<dim3(8, 8, 4), 256, 0, stream>>>(Wq, Wk, Wv, Wh, Wt, Wht);
  proj_kernel<<<dim3(HD / 128, BB * NQ / 128, 3), 256, 0, stream>>>(
      Xb, Wt, Qf, Kf, Vf);
  vtrans_kernel<<<dim3(NKK / 64, HD / 64, BB), 256, 0, stream>>>(Vf, Vt);
  attn_kernel<<<dim3(NQ / 128, NH, BB * 2), 256, 0, stream>>>(Qf, Kf, Vt, Op, Ls);
  reduce_kernel<<<dim3((unsigned)(E / 256)), 256, 0, stream>>>(Op, Ls, CTX);
  outproj_kernel<<<dim3(BB * NQ / 16), 64, 0, stream>>>(CTX, Wht, out);
}

// Round 8
// 233.047 us; speedup vs baseline: 1.0454x; 1.0454x over previous
//
#include <hip/hip_runtime.h>
#include <hip/hip_bf16.h>

// Problem constants (set_attention): B=4, Nq=Nk=2048, D_IN=512, H=8, HS=64
#define BB   4
#define NQ   2048
#define NKK  2048
#define DIN  512
#define NH   8
#define HS   64
#define HD   512  // NH*HS

typedef __hip_bfloat16 bf16;
typedef unsigned short ushort_t;
typedef __attribute__((ext_vector_type(8))) short short8;  // 8 bf16 (4 VGPRs)
typedef __attribute__((ext_vector_type(4))) float f32x4;   // MFMA C/D

__device__ __forceinline__ unsigned short f2bu(float x) {
  bf16 h = __float2bfloat16(x);
  return *(unsigned short*)&h;
}

// ---------------------------------------------------------------------------
// Kernel 0: weight transpose + bf16 convert.
// z<3:  W[512k][512n] f32 -> Wt_z[n][k] bf16   (64x64 tiles via LDS)
// z==3: Wh[512k][64n] f32 -> Wht[n][k] bf16
// ---------------------------------------------------------------------------
__global__ __launch_bounds__(256) void wtrans_kernel(
    const float* __restrict__ Wq, const float* __restrict__ Wk,
    const float* __restrict__ Wv, const float* __restrict__ Wh,
    ushort_t* __restrict__ Wt, ushort_t* __restrict__ Wht) {
  const int z = blockIdx.z;
  const float* src;
  ushort_t* dst;
  int S;
  if (z < 3) {
    src = (z == 0) ? Wq : (z == 1) ? Wk : Wv;
    dst = Wt + (size_t)z * 512 * 512;
    S = 512;
  } else {
    if (blockIdx.y != 0) return;
    src = Wh;
    dst = Wht;
    S = 64;
  }
  const int k0 = blockIdx.x * 64;
  const int n0 = (z < 3) ? blockIdx.y * 64 : 0;

  __shared__ ushort_t Ls[64 * 72];
  const int tid = threadIdx.x;
  {
    int r = tid >> 2, cb = (tid & 3) * 16;
    const float* sp = src + (size_t)(k0 + r) * S + n0 + cb;
#pragma unroll
    for (int ii = 0; ii < 4; ++ii) {
      float4 f = *(const float4*)(sp + ii * 4);
      __align__(8) ushort_t t4[4] = {f2bu(f.x), f2bu(f.y), f2bu(f.z), f2bu(f.w)};
      *(uint2*)(&Ls[r * 72 + cb + ii * 4]) = *(uint2*)t4;
    }
  }
  __syncthreads();
  {
    int rr = tid >> 2, tb = (tid & 3) * 16;
    __align__(16) ushort_t tmp[16];
#pragma unroll
    for (int j = 0; j < 16; ++j) tmp[j] = Ls[(tb + j) * 72 + rr];
    ushort_t* dp = dst + (size_t)(n0 + rr) * 512 + k0 + tb;
    *(int4*)dp       = ((int4*)tmp)[0];
    *(int4*)(dp + 8) = ((int4*)tmp)[1];
  }
}

// ---------------------------------------------------------------------------
// Kernel 1: QKV projections, bf16 MFMA, double-buffered (round-6 form:
// A staged f32->bf16 in-kernel, B from pre-transposed bf16 Wt [n][k]).
// 128x128 tile, BK=32, 4 waves x 64x64 out.
// ---------------------------------------------------------------------------
__global__ __launch_bounds__(256) void proj_kernel(
    const float* __restrict__ q, const float* __restrict__ k,
    const ushort_t* __restrict__ Wt, ushort_t* __restrict__ Qf,
    ushort_t* __restrict__ Kf, ushort_t* __restrict__ Vf) {
  const int z = blockIdx.z;
  const float* X = (z == 0) ? q : k;
  const ushort_t* Wz = Wt + (size_t)z * 512 * 512;
  ushort_t* Y = (z == 0) ? Qf : (z == 1) ? Kf : Vf;
  const float sc = (z == 0) ? 0.125f : 1.0f;  // fold 1/sqrt(64) into Q

  __shared__ ushort_t As[2 * 128 * 40];  // [buf][m][k]
  __shared__ ushort_t Bs[2 * 128 * 40];  // [buf][n][k]

  const int tid  = threadIdx.x;
  const int lane = tid & 63;
  const int w    = tid >> 6;
  const int quad = lane >> 4;
  const int c    = lane & 15;
  const int wm   = w >> 1, wn = w & 1;

  const int m0 = blockIdx.y * 128;
  const int n0 = blockIdx.x * 128;
  const int sm  = tid >> 1;
  const int skb = (tid & 1) * 16;

  float4 xa[4];
  int4 wb[2];
  auto load_t = [&](int k0) {
    const float* xp = X + (size_t)(m0 + sm) * DIN + k0 + skb;
    xa[0] = *(const float4*)(xp + 0);
    xa[1] = *(const float4*)(xp + 4);
    xa[2] = *(const float4*)(xp + 8);
    xa[3] = *(const float4*)(xp + 12);
    const ushort_t* wp = Wz + (size_t)(n0 + sm) * 512 + k0 + skb;
    wb[0] = *(const int4*)wp;
    wb[1] = *(const int4*)(wp + 8);
  };
  auto store_t = [&](int buf) {
    __align__(16) ushort_t ta[16];
#pragma unroll
    for (int ii = 0; ii < 4; ++ii) {
      ta[ii * 4 + 0] = f2bu(xa[ii].x);
      ta[ii * 4 + 1] = f2bu(xa[ii].y);
      ta[ii * 4 + 2] = f2bu(xa[ii].z);
      ta[ii * 4 + 3] = f2bu(xa[ii].w);
    }
    *(int4*)(&As[buf * 5120 + sm * 40 + skb])     = ((int4*)ta)[0];
    *(int4*)(&As[buf * 5120 + sm * 40 + skb + 8]) = ((int4*)ta)[1];
    *(int4*)(&Bs[buf * 5120 + sm * 40 + skb])     = wb[0];
    *(int4*)(&Bs[buf * 5120 + sm * 40 + skb + 8]) = wb[1];
  };

  f32x4 acc[4][4];
#pragma unroll
  for (int m = 0; m < 4; ++m)
#pragma unroll
    for (int n = 0; n < 4; ++n) acc[m][n] = (f32x4)0.0f;

  load_t(0);
  store_t(0);
  __syncthreads();

  for (int t = 0; t < 16; ++t) {
    const int cur = t & 1;
    if (t < 15) load_t((t + 1) * 32);
    const ushort_t* as = As + cur * 5120;
    const ushort_t* bs = Bs + cur * 5120;
    short8 af[4], bfr[4];
#pragma unroll
    for (int m = 0; m < 4; ++m)
      af[m] = *(const short8*)(&as[(wm * 64 + m * 16 + c) * 40 + quad * 8]);
#pragma unroll
    for (int n = 0; n < 4; ++n)
      bfr[n] = *(const short8*)(&bs[(wn * 64 + n * 16 + c) * 40 + quad * 8]);
#pragma unroll
    for (int m = 0; m < 4; ++m)
#pragma unroll
      for (int n = 0; n < 4; ++n)
        acc[m][n] = __builtin_amdgcn_mfma_f32_16x16x32_bf16(af[m], bfr[n], acc[m][n], 0, 0, 0);
    if (t < 15) store_t(cur ^ 1);
    __syncthreads();
  }

#pragma unroll
  for (int m = 0; m < 4; ++m)
#pragma unroll
    for (int n = 0; n < 4; ++n)
#pragma unroll
      for (int r = 0; r < 4; ++r) {
        int row = m0 + wm * 64 + m * 16 + quad * 4 + r;
        int col = n0 + wn * 64 + n * 16 + c;
        Y[(size_t)row * HD + col] = f2bu(acc[m][n][r] * sc);
      }
}

// ---------------------------------------------------------------------------
// Kernel 1b: V transpose. Vf[(b*2048+t)*512 + cc] -> Vt[(b*512+cc)*2048 + t].
// ---------------------------------------------------------------------------
__global__ __launch_bounds__(256) void vtrans_kernel(
    const ushort_t* __restrict__ Vf, ushort_t* __restrict__ Vt) {
  const int b  = blockIdx.z;
  const int t0 = blockIdx.x * 64;
  const int c0 = blockIdx.y * 64;
  __shared__ ushort_t Ls[64 * 72];
  const int tid = threadIdx.x;
  {
    int r = tid >> 2, cb = (tid & 3) * 16;
    const ushort_t* src = Vf + (size_t)(b * NQ + t0 + r) * HD + c0 + cb;
    *(int4*)(&Ls[r * 72 + cb])     = *(const int4*)src;
    *(int4*)(&Ls[r * 72 + cb + 8]) = *(const int4*)(src + 8);
  }
  __syncthreads();
  {
    int rr = tid >> 2, tb = (tid & 3) * 16;
    __align__(16) ushort_t tmp[16];
#pragma unroll
    for (int j = 0; j < 16; ++j) tmp[j] = Ls[(tb + j) * 72 + rr];
    ushort_t* dst = Vt + (size_t)(b * HD + c0 + rr) * NKK + t0 + tb;
    *(int4*)dst       = ((int4*)tmp)[0];
    *(int4*)(dst + 8) = ((int4*)tmp)[1];
  }
}

// ---------------------------------------------------------------------------
// Kernel 2: MFMA flash attention, IN-BLOCK key-split.
// 512 thr = 8 waves: wave w -> qg = w&3 (32 q rows), kh = w>>2 (key half).
// Each half has its own K/V LDS tile (staged by its own 256 threads,
// register-prefetched, single-buffered). Partials merged through LDS at the
// end: kh=1 writes unnormalized O + L to scratch overlaid on dead K/V
// buffers; kh=0 adds, normalizes, writes CTX. No global f32 partials.
// ---------------------------------------------------------------------------
__global__ __launch_bounds__(512, 4) void attn_kernel(
    const ushort_t* __restrict__ Qf, const ushort_t* __restrict__ Kf,
    const ushort_t* __restrict__ Vt, ushort_t* __restrict__ CTX) {
  const int qb = blockIdx.x;
  const int h  = blockIdx.y;
  const int b  = blockIdx.z;

  // smem carve (73728 B): Kt[2][64*72] | Vs[2][64*72] | Ps[8][32*72]
  // epilogue overlay on Kt+Vs: Oscr[128*66 f32] (33792 B) + Lscr[128 f32]
  __shared__ __align__(16) char smem[73728];
  ushort_t* KtA = (ushort_t*)smem;              // 2 x 4608 shorts
  ushort_t* VsA = (ushort_t*)(smem + 18432);    // 2 x 4608 shorts
  ushort_t* PsA = (ushort_t*)(smem + 36864);    // 8 x 2304 shorts
  float*    Oscr = (float*)smem;
  float*    Lscr = (float*)(smem + 33792);

  const int tid  = threadIdx.x;
  const int lane = tid & 63;
  const int w    = tid >> 6;   // 0..7
  const int quad = lane >> 4;
  const int c    = lane & 15;
  const int qg   = w & 3;
  const int kh   = w >> 2;

  const int q0 = qb * 128 + qg * 32;

  // staging role: threads 0..255 stage half 0, 256..511 half 1 (== own kh)
  const int sh = tid >> 8;
  const int st = tid & 255;
  const int kbase = sh * 1024;

  ushort_t* kth = KtA + kh * 4608;
  ushort_t* vsh = VsA + kh * 4608;
  ushort_t* psw = PsA + w * 2304;

  // Q as the B operand (regs all kernel)
  short8 bq[2][2];
#pragma unroll
  for (int nq = 0; nq < 2; ++nq)
#pragma unroll
    for (int kk = 0; kk < 2; ++kk)
      bq[nq][kk] = *(const short8*)(Qf + (size_t)(b * NQ + q0 + nq * 16 + c) * HD +
                                    h * HS + kk * 32 + quad * 8);

  f32x4 o[2][4];
#pragma unroll
  for (int m = 0; m < 2; ++m)
#pragma unroll
    for (int n = 0; n < 4; ++n) o[m][n] = (f32x4)0.0f;
  float lsum[2] = {0.0f, 0.0f};

  int4 pk[2], pv[2];
  auto load_t = [&](int kt) {  // kt: local tile 0..15 within this half
#pragma unroll
    for (int i = 0; i < 2; ++i) {
      int g = i * 256 + st, row = g >> 3, gr = g & 7;
      pk[i] = *(const int4*)(Kf + (size_t)(b * NKK + kbase + kt * 64 + row) * HD +
                             h * HS + gr * 8);
      pv[i] = *(const int4*)(Vt + (size_t)((b * NH + h) * HS + row) * NKK +
                             kbase + kt * 64 + gr * 8);
    }
  };
  auto store_t = [&]() {
#pragma unroll
    for (int i = 0; i < 2; ++i) {
      int g = i * 256 + st, row = g >> 3, gr = g & 7;
      *(int4*)(KtA + sh * 4608 + row * 72 + gr * 8) = pk[i];
      *(int4*)(VsA + sh * 4608 + row * 72 + gr * 8) = pv[i];
    }
  };

  load_t(0);
  store_t();
  __syncthreads();

  for (int kt = 0; kt < 16; ++kt) {
    if (kt < 15) load_t(kt + 1);  // global->regs, in flight during compute

    // S^T = K @ Q^T
    f32x4 s[4][2];
#pragma unroll
    for (int mk = 0; mk < 4; ++mk)
#pragma unroll
      for (int nq = 0; nq < 2; ++nq) s[mk][nq] = (f32x4)0.0f;
#pragma unroll
    for (int mk = 0; mk < 4; ++mk)
#pragma unroll
      for (int kk = 0; kk < 2; ++kk) {
        short8 ak = *(const short8*)(kth + (mk * 16 + c) * 72 + kk * 32 + quad * 8);
#pragma unroll
        for (int nq = 0; nq < 2; ++nq)
          s[mk][nq] = __builtin_amdgcn_mfma_f32_16x16x32_bf16(ak, bq[nq][kk], s[mk][nq], 0, 0, 0);
      }

    // P = exp(S^T); packed 8B writes to wave-private Ps[q][key]
#pragma unroll
    for (int mk = 0; mk < 4; ++mk)
#pragma unroll
      for (int nq = 0; nq < 2; ++nq) {
        float p0 = __expf(s[mk][nq][0]);
        float p1 = __expf(s[mk][nq][1]);
        float p2 = __expf(s[mk][nq][2]);
        float p3 = __expf(s[mk][nq][3]);
        lsum[nq] += (p0 + p1) + (p2 + p3);
        unsigned int lo = (unsigned int)f2bu(p0) | ((unsigned int)f2bu(p1) << 16);
        unsigned int hi = (unsigned int)f2bu(p2) | ((unsigned int)f2bu(p3) << 16);
        *(uint2*)(psw + (nq * 16 + c) * 72 + mk * 16 + quad * 4) = make_uint2(lo, hi);
      }

    // O += P @ V
    short8 ap[2][2];
#pragma unroll
    for (int mq = 0; mq < 2; ++mq)
#pragma unroll
      for (int kk = 0; kk < 2; ++kk)
        ap[mq][kk] = *(const short8*)(psw + (mq * 16 + c) * 72 + kk * 32 + quad * 8);
#pragma unroll
    for (int nd = 0; nd < 4; ++nd)
#pragma unroll
      for (int kk = 0; kk < 2; ++kk) {
        short8 bv = *(const short8*)(vsh + (nd * 16 + c) * 72 + kk * 32 + quad * 8);
#pragma unroll
        for (int mq = 0; mq < 2; ++mq)
          o[mq][nd] = __builtin_amdgcn_mfma_f32_16x16x32_bf16(ap[mq][kk], bv, o[mq][nd], 0, 0, 0);
      }

    if (kt < 15) {
      __syncthreads();  // all waves done reading this half's K/V LDS
      store_t();        // waits vmcnt, refills
      __syncthreads();
    }
  }

  // reduce column sums across quads: every lane ends with total for col c
  float colsum[2];
#pragma unroll
  for (int nq = 0; nq < 2; ++nq) {
    float v = lsum[nq];
    v += __shfl_xor(v, 16);
    v += __shfl_xor(v, 32);
    colsum[nq] = v;
  }

  __syncthreads();  // loop fully done -> safe to overlay Kt/Vs with Oscr

  if (kh == 1) {
#pragma unroll
    for (int mq = 0; mq < 2; ++mq)
#pragma unroll
      for (int nd = 0; nd < 4; ++nd)
#pragma unroll
        for (int r = 0; r < 4; ++r)
          Oscr[(qg * 32 + mq * 16 + quad * 4 + r) * 66 + nd * 16 + c] = o[mq][nd][r];
    if (quad == 0) {
#pragma unroll
      for (int nq = 0; nq < 2; ++nq) Lscr[qg * 32 + nq * 16 + c] = colsum[nq];
    }
  }
  __syncthreads();

  if (kh == 0) {
    float inv[2];
#pragma unroll
    for (int nq = 0; nq < 2; ++nq)
      inv[nq] = 1.0f / (colsum[nq] + Lscr[qg * 32 + nq * 16 + c]);
    float invr[2][4];
#pragma unroll
    for (int mq = 0; mq < 2; ++mq)
#pragma unroll
      for (int r = 0; r < 4; ++r) invr[mq][r] = __shfl(inv[mq], quad * 4 + r);

#pragma unroll
    for (int mq = 0; mq < 2; ++mq)
#pragma unroll
      for (int nd = 0; nd < 4; ++nd)
#pragma unroll
        for (int r = 0; r < 4; ++r) {
          float val = o[mq][nd][r] +
                      Oscr[(qg * 32 + mq * 16 + quad * 4 + r) * 66 + nd * 16 + c];
          size_t idx = (size_t)(b * NQ + q0 + mq * 16 + quad * 4 + r) * HD +
                       h * HS + nd * 16 + c;
          CTX[idx] = f2bu(val * invr[mq][r]);
        }
  }
}

// ---------------------------------------------------------------------------
// Kernel 3: out[8192,64] = CTX[8192,512] @ Wh[512,64], LDS-free MFMA.
// ---------------------------------------------------------------------------
__global__ __launch_bounds__(64) void outproj_kernel(
    const ushort_t* __restrict__ CTX, const ushort_t* __restrict__ Wht,
    float* __restrict__ out) {
  const int lane = threadIdx.x & 63;
  const int quad = lane >> 4, c = lane & 15;
  const int m0 = blockIdx.x * 16;

  f32x4 o[4];
#pragma unroll
  for (int n = 0; n < 4; ++n) o[n] = (f32x4)0.0f;

  const ushort_t* arow = CTX + (size_t)(m0 + c) * HD;
#pragma unroll 4
  for (int ks = 0; ks < 16; ++ks) {
    short8 a = *(const short8*)(arow + ks * 32 + quad * 8);
#pragma unroll
    for (int nd = 0; nd < 4; ++nd) {
      short8 bn = *(const short8*)(Wht + (size_t)(nd * 16 + c) * 512 + ks * 32 + quad * 8);
      o[nd] = __builtin_amdgcn_mfma_f32_16x16x32_bf16(a, bn, o[nd], 0, 0, 0);
    }
  }
#pragma unroll
  for (int nd = 0; nd < 4; ++nd)
#pragma unroll
    for (int r = 0; r < 4; ++r)
      out[(size_t)(m0 + quad * 4 + r) * HS + nd * 16 + c] = o[nd][r];
}

// ---------------------------------------------------------------------------
extern "C" void kernel_launch(void* const* d_in, const int* in_sizes, int n_in,
                              void* d_out, int out_size, void* d_ws,
                              size_t ws_size, hipStream_t stream) {
  const float* q  = (const float*)d_in[0];
  const float* k  = (const float*)d_in[1];
  const float* Wq = (const float*)d_in[2];
  const float* Wk = (const float*)d_in[3];
  const float* Wv = (const float*)d_in[4];
  const float* Wh = (const float*)d_in[5];
  float* out = (float*)d_out;

  // Workspace (bytes). E2 = one bf16 [8192x512] tensor = 8 MiB.
  const size_t E2 = (size_t)BB * NQ * HD * 2;
  char* base = (char*)d_ws;
  ushort_t* Qf  = (ushort_t*)(base);
  ushort_t* Kf  = (ushort_t*)(base + E2);
  ushort_t* Vt  = (ushort_t*)(base + 2 * E2);
  ushort_t* CTX = (ushort_t*)(base + 3 * E2);
  ushort_t* Wt  = (ushort_t*)(base + 4 * E2);             // 1.5 MiB
  ushort_t* Wht = (ushort_t*)(base + 4 * E2 + 1572864);   // 64 KiB
  ushort_t* Vf  = (ushort_t*)(base + 4 * E2 + 1638400);   // 8 MiB

  wtrans_kernel<<<dim3(8, 8, 4), 256, 0, stream>>>(Wq, Wk, Wv, Wh, Wt, Wht);
  proj_kernel<<<dim3(HD / 128, BB * NQ / 128, 3), 256, 0, stream>>>(
      q, k, Wt, Qf, Kf, Vf);
  vtrans_kernel<<<dim3(NKK / 64, HD / 64, BB), 256, 0, stream>>>(Vf, Vt);
  attn_kernel<<<dim3(NQ / 128, NH, BB), 512, 0, stream>>>(Qf, Kf, Vt, CTX);
  outproj_kernel<<<dim3(BB * NQ / 16), 64, 0, stream>>>(CTX, Wht, out);
}